// Round 4
// baseline (1007.382 us; speedup 1.0000x reference)
//
#include <hip/hip_runtime.h>
#include <math.h>

// Problem constants
#define R_  128
#define C_  256
#define E_  768
#define H_  12
#define DK_ 64
#define T_  (R_*C_)       // 32768 tokens
#define RS_ 32            // split-K chunks over rows in attn (4 rows each)
#define LP  40            // LDS tile row pitch in ushorts (32 + 8 pad, 80 B)
#define REPP 132          // epilogue repack row pitch in floats (128 + 4)

typedef __attribute__((ext_vector_type(8))) short          bf16x8;
typedef __attribute__((ext_vector_type(4))) float          f32x4;
typedef __attribute__((ext_vector_type(4))) unsigned short u16x4;
typedef __attribute__((ext_vector_type(8))) unsigned short u16x8;
typedef unsigned short ush;

struct HL { unsigned short h, l; };

// fp32 -> (hi, lo) bf16 split via truncation; hi+lo ~ 2^-16 relative.
__device__ __forceinline__ HL split2(float f) {
    HL o;
    unsigned int u = __float_as_uint(f);
    o.h = (unsigned short)(u >> 16);
    float r = f - __uint_as_float(u & 0xFFFF0000u);
    o.l = (unsigned short)(__float_as_uint(r) >> 16);
    return o;
}

// Stage 16 contiguous fp32 elements as split bf16 planes at LDS offset `off`.
__device__ __forceinline__ void stage16_f32(ush* H, ush* L, int off, const float* src) {
    #pragma unroll
    for (int c = 0; c < 4; ++c) {
        float4 f = *(const float4*)(src + 4 * c);
        u16x4 h4, l4;
        HL e0 = split2(f.x), e1 = split2(f.y), e2 = split2(f.z), e3 = split2(f.w);
        h4[0] = e0.h; h4[1] = e1.h; h4[2] = e2.h; h4[3] = e3.h;
        l4[0] = e0.l; l4[1] = e1.l; l4[2] = e2.l; l4[3] = e3.l;
        *(u16x4*)&H[off + 4 * c] = h4;
        *(u16x4*)&L[off + 4 * c] = l4;
    }
}

// Stage 16 pre-split elements (hi/lo planes) at LDS offset `off`.
__device__ __forceinline__ void stage16_pre(ush* H, ush* L, int off,
                                            const ush* srcH, const ush* srcL) {
    *(u16x8*)&H[off]     = *(const u16x8*)srcH;
    *(u16x8*)&H[off + 8] = *(const u16x8*)(srcH + 8);
    *(u16x8*)&L[off]     = *(const u16x8*)srcL;
    *(u16x8*)&L[off + 8] = *(const u16x8*)(srcL + 8);
}

// One BK=32 step of the 64x128 wave tile: 8+16 frag loads, 96 MFMA (3-term).
__device__ __forceinline__ void mma_step(
    const ush* AsH, const ush* AsL, const ush* BsH, const ush* BsL,
    int wm, int wn, int fr, int kq, f32x4 (&acc)[4][8])
{
    bf16x8 ah[4], al[4];
    #pragma unroll
    for (int t = 0; t < 4; ++t) {
        ah[t] = *(const bf16x8*)&AsH[(wm + t * 16 + fr) * LP + kq];
        al[t] = *(const bf16x8*)&AsL[(wm + t * 16 + fr) * LP + kq];
    }
    #pragma unroll
    for (int j = 0; j < 8; ++j) {
        bf16x8 bh = *(const bf16x8*)&BsH[(wn + j * 16 + fr) * LP + kq];
        bf16x8 bl = *(const bf16x8*)&BsL[(wn + j * 16 + fr) * LP + kq];
        #pragma unroll
        for (int i = 0; i < 4; ++i) {
            acc[i][j] = __builtin_amdgcn_mfma_f32_16x16x32_bf16(ah[i], bh, acc[i][j], 0, 0, 0);
            acc[i][j] = __builtin_amdgcn_mfma_f32_16x16x32_bf16(ah[i], bl, acc[i][j], 0, 0, 0);
            acc[i][j] = __builtin_amdgcn_mfma_f32_16x16x32_bf16(al[i], bh, acc[i][j], 0, 0, 0);
        }
    }
}

// Per-wave repack of one 16-row slab (acc row ti) into v[32] per lane.
// rep region is wave-private -> no block barrier; stride 132 kills the
// 0-mod-32-bank alignment (writes conflict-free, reads <=4-way).
__device__ __forceinline__ void repack_ti(float* rep, const f32x4 (&arow)[8],
                                          int lane, float (&v)[32])
{
    const int fr = lane & 15, q4 = lane >> 4;
    #pragma unroll
    for (int tj = 0; tj < 8; ++tj)
        #pragma unroll
        for (int r = 0; r < 4; ++r)
            rep[(q4 * 4 + r) * REPP + tj * 16 + fr] = arow[tj][r];
    asm volatile("" ::: "memory");
    const int mr = lane >> 2, q = lane & 3;
    #pragma unroll
    for (int c = 0; c < 8; ++c)
        *(float4*)&v[4 * c] = *(const float4*)&rep[mr * REPP + q * 32 + 4 * c];
}

// ---------------------------------------------------------------------------
// Fused QKV projection: block 128(t) x 256(n), n in [0,2304) over [Wq|Wk|Wv].
// A = x fp32 (split in staging), B = W fp32 (split in staging).
// Output: split bf16 planes of (x@W.T + b) * scale into q/k/v buffers.
// ---------------------------------------------------------------------------
__global__ __launch_bounds__(256, 2) void qkv_gemm(
    const float* __restrict__ x,
    const float* __restrict__ Wq, const float* __restrict__ bq,
    const float* __restrict__ Wk, const float* __restrict__ bk,
    const float* __restrict__ Wv, const float* __restrict__ bv,
    float scaling,
    ush* __restrict__ qh, ush* __restrict__ ql,
    ush* __restrict__ kh, ush* __restrict__ kl,
    ush* __restrict__ vh, ush* __restrict__ vl)
{
    __shared__ __align__(16) ush smem[30720];   // 60 KB
    ush* AsH = smem;            // [128][LP]
    ush* AsL = smem + 5120;
    ush* BsH = smem + 10240;    // [256][LP]
    ush* BsL = smem + 20480;

    const int n0g = blockIdx.x * 256;     // 0..2048
    const int m0  = blockIdx.y * 128;
    const int mat = n0g / 768;            // block-uniform (768 % 256 == 0)
    const int n0  = n0g - mat * 768;      // column within the selected matrix
    const float* W    = (mat == 0) ? Wq : (mat == 1) ? Wk : Wv;
    const float* bias = (mat == 0) ? bq : (mat == 1) ? bk : bv;
    const float scale = (mat == 0) ? scaling : 1.0f;
    ush* Yh = (mat == 0) ? qh : (mat == 1) ? kh : vh;
    ush* Yl = (mat == 0) ? ql : (mat == 1) ? kl : vl;

    const int tid = threadIdx.x;
    const int wave = tid >> 6, lane = tid & 63;
    const int wm = (wave & 1) * 64, wn = (wave >> 1) * 128;
    const int fr = lane & 15, kq = (lane >> 4) * 8;
    const int arow = tid >> 1, koff = (tid & 1) * 16;

    f32x4 acc[4][8] = {};

    for (int k0 = 0; k0 < E_; k0 += 32) {
        stage16_f32(AsH, AsL, arow * LP + koff, x + (size_t)(m0 + arow) * E_ + k0 + koff);
        #pragma unroll
        for (int rr = 0; rr < 2; ++rr) {
            const int brow = rr * 128 + arow;
            stage16_f32(BsH, BsL, brow * LP + koff, W + (size_t)(n0 + brow) * E_ + k0 + koff);
        }
        __syncthreads();
        mma_step(AsH, AsL, BsH, BsL, wm, wn, fr, kq, acc);
        __syncthreads();
    }

    __syncthreads();
    float* rep = (float*)smem + wave * (16 * REPP);
    const int mr = lane >> 2, q = lane & 3;
    #pragma unroll
    for (int ti = 0; ti < 4; ++ti) {
        float v[32];
        repack_ti(rep, acc[ti], lane, v);
        const int gm = m0 + wm + ti * 16 + mr;
        const int gc = n0 + wn + q * 32;           // column in this matrix
        #pragma unroll
        for (int g = 0; g < 4; ++g) {
            float4 b0 = *(const float4*)&bias[gc + 8 * g];
            float4 b1 = *(const float4*)&bias[gc + 8 * g + 4];
            float o[8] = {(v[8*g+0]+b0.x)*scale, (v[8*g+1]+b0.y)*scale,
                          (v[8*g+2]+b0.z)*scale, (v[8*g+3]+b0.w)*scale,
                          (v[8*g+4]+b1.x)*scale, (v[8*g+5]+b1.y)*scale,
                          (v[8*g+6]+b1.z)*scale, (v[8*g+7]+b1.w)*scale};
            u16x8 H8, L8;
            #pragma unroll
            for (int e = 0; e < 8; ++e) { HL s = split2(o[e]); H8[e] = s.h; L8[e] = s.l; }
            *(u16x8*)&Yh[(size_t)gm * E_ + gc + 8 * g] = H8;
            *(u16x8*)&Yl[(size_t)gm * E_ + gc + 8 * g] = L8;
        }
    }
}

// ---------------------------------------------------------------------------
// Pooled attention logits, split-K over rows (RS_=32 chunks of 4 rows):
// part[rc,h,i,j] = sum_{r in chunk} sum_d q.k   (pre-split bf16 inputs)
// Block: i 128 x j 256, K-chunk = 4 rows * 64 d = 256 -> 8 BK=32 steps.
// ---------------------------------------------------------------------------
__global__ __launch_bounds__(256, 2) void attn2(
    const ush* __restrict__ Qh, const ush* __restrict__ Ql,
    const ush* __restrict__ Kh, const ush* __restrict__ Kl,
    float* __restrict__ part)
{
    __shared__ __align__(16) ush smem[30720];
    ush* AsH = smem;
    ush* AsL = smem + 5120;
    ush* BsH = smem + 10240;
    ush* BsL = smem + 20480;

    const int i0 = blockIdx.x * 128;
    const int z  = blockIdx.y;            // h*32 + rc
    const int h  = z >> 5;
    const int rc = z & 31;

    const int tid = threadIdx.x;
    const int wave = tid >> 6, lane = tid & 63;
    const int wm = (wave & 1) * 64, wn = (wave >> 1) * 128;
    const int fr = lane & 15, kq = (lane >> 4) * 8;
    const int arow = tid >> 1, koff = (tid & 1) * 16;

    f32x4 acc[4][8] = {};

    for (int s = 0; s < 8; ++s) {
        const int r  = rc * 4 + (s >> 1);
        const int d0 = (s & 1) * 32;
        const size_t qb = ((size_t)(r * C_) + i0 + arow) * E_ + h * DK_ + d0 + koff;
        stage16_pre(AsH, AsL, arow * LP + koff, Qh + qb, Ql + qb);
        #pragma unroll
        for (int rr = 0; rr < 2; ++rr) {
            const int brow = rr * 128 + arow;
            const size_t kb = ((size_t)(r * C_) + brow) * E_ + h * DK_ + d0 + koff;
            stage16_pre(BsH, BsL, brow * LP + koff, Kh + kb, Kl + kb);
        }
        __syncthreads();
        mma_step(AsH, AsL, BsH, BsL, wm, wn, fr, kq, acc);
        __syncthreads();
    }

    __syncthreads();
    float* rep = (float*)smem + wave * (16 * REPP);
    const int mr = lane >> 2, q = lane & 3;
    #pragma unroll
    for (int ti = 0; ti < 4; ++ti) {
        float v[32];
        repack_ti(rep, acc[ti], lane, v);
        const int gi = i0 + wm + ti * 16 + mr;
        const int gj = wn + q * 32;
        float* dst = part + ((size_t)(rc * H_ + h) * C_ + gi) * C_ + gj;
        #pragma unroll
        for (int c = 0; c < 8; ++c)
            *(float4*)&dst[4 * c] = *(const float4*)&v[4 * c];
    }
}

// ---------------------------------------------------------------------------
// Reduce RS_ partials + row softmax + write fp32 probs and bf16 split.
// ---------------------------------------------------------------------------
__global__ __launch_bounds__(256) void softmax_split(
    const float* __restrict__ part, float* __restrict__ probs,
    ush* __restrict__ ph, ush* __restrict__ pl)
{
    const int row = blockIdx.x;            // h * C_ + i
    const int j = threadIdx.x;
    const int wave = j >> 6, lane = j & 63;

    float s = 0.0f;
    #pragma unroll
    for (int rcn = 0; rcn < RS_; ++rcn)
        s += part[(size_t)rcn * H_ * C_ * C_ + (size_t)row * C_ + j];

    float m = s;
    #pragma unroll
    for (int off = 32; off > 0; off >>= 1)
        m = fmaxf(m, __shfl_down(m, off, 64));
    __shared__ float redm[4];
    if (lane == 0) redm[wave] = m;
    __syncthreads();
    m = fmaxf(fmaxf(redm[0], redm[1]), fmaxf(redm[2], redm[3]));

    float e = expf(s - m);
    float t = e;
    #pragma unroll
    for (int off = 32; off > 0; off >>= 1)
        t += __shfl_down(t, off, 64);
    __shared__ float reds[4];
    if (lane == 0) reds[wave] = t;
    __syncthreads();
    t = reds[0] + reds[1] + reds[2] + reds[3];

    float p = e / t;
    probs[(size_t)row * C_ + j] = p;
    HL sp = split2(p);
    ph[(size_t)row * C_ + j] = sp.h;
    pl[(size_t)row * C_ + j] = sp.l;
}

// ---------------------------------------------------------------------------
// Context: C[r*C+i, h*64+d] = sum_j P[h,i,j] * V[r*C+j, h*64+d], split output.
// (unchanged from R3)
// ---------------------------------------------------------------------------
__global__ __launch_bounds__(256, 2) void ctx_mfma(
    const ush* __restrict__ Ph, const ush* __restrict__ Pl,
    const ush* __restrict__ Vh, const ush* __restrict__ Vl,
    ush* __restrict__ Ch, ush* __restrict__ Cl)
{
    __shared__ __align__(16) ush smem[15360];   // 30 KB
    ush* PsH = smem;            // [128][LP]
    ush* PsL = smem + 5120;
    ush* VsH = smem + 10240;    // [64][LP]
    ush* VsL = smem + 12800;

    const int tid  = threadIdx.x;
    const int i0   = blockIdx.x * 128;
    const int r    = blockIdx.y;
    const int h    = blockIdx.z;
    const int wave = tid >> 6, lane = tid & 63;
    const int wm   = (wave & 1) * 64, wn = (wave >> 1) * 32;
    const int fr   = lane & 15;
    const int kq   = (lane >> 4) * 8;
    const int srow = tid >> 1;
    const int sk   = (tid & 1) * 16;
    const int vjj  = tid & 31;
    const int vdg  = tid >> 5;             // 0..7

    f32x4 acc[4][2] = {};

    for (int s = 0; s < 8; ++s) {
        const int jb = s * 32;
        const size_t pb = ((size_t)(h * C_) + i0 + srow) * C_ + jb + sk;
        stage16_pre(PsH, PsL, srow * LP + sk, Ph + pb, Pl + pb);
        const size_t vb = ((size_t)(r * C_) + jb + vjj) * E_ + h * DK_ + vdg * 8;
        u16x8 v_h = *(const u16x8*)&Vh[vb];
        u16x8 v_l = *(const u16x8*)&Vl[vb];
        #pragma unroll
        for (int u = 0; u < 8; ++u) {
            VsH[(vdg * 8 + u) * LP + vjj] = v_h[u];
            VsL[(vdg * 8 + u) * LP + vjj] = v_l[u];
        }
        __syncthreads();

        bf16x8 p_h[4], p_l[4], w_h[2], w_l[2];
        #pragma unroll
        for (int t = 0; t < 4; ++t) {
            p_h[t] = *(const bf16x8*)&PsH[(wm + t * 16 + fr) * LP + kq];
            p_l[t] = *(const bf16x8*)&PsL[(wm + t * 16 + fr) * LP + kq];
        }
        #pragma unroll
        for (int t = 0; t < 2; ++t) {
            w_h[t] = *(const bf16x8*)&VsH[(wn + t * 16 + fr) * LP + kq];
            w_l[t] = *(const bf16x8*)&VsL[(wn + t * 16 + fr) * LP + kq];
        }
        #pragma unroll
        for (int i = 0; i < 4; ++i)
            #pragma unroll
            for (int j = 0; j < 2; ++j) {
                acc[i][j] = __builtin_amdgcn_mfma_f32_16x16x32_bf16(p_h[i], w_h[j], acc[i][j], 0, 0, 0);
                acc[i][j] = __builtin_amdgcn_mfma_f32_16x16x32_bf16(p_h[i], w_l[j], acc[i][j], 0, 0, 0);
                acc[i][j] = __builtin_amdgcn_mfma_f32_16x16x32_bf16(p_l[i], w_h[j], acc[i][j], 0, 0, 0);
            }
        __syncthreads();
    }

    float* rep = (float*)smem + wave * 512;   // [16][32] per wave
    const int mr = lane >> 2;
    const int nc = (lane & 3) * 8;
    #pragma unroll
    for (int ti = 0; ti < 4; ++ti) {
        __syncthreads();
        #pragma unroll
        for (int tj = 0; tj < 2; ++tj)
            #pragma unroll
            for (int rr = 0; rr < 4; ++rr)
                rep[((lane >> 4) * 4 + rr) * 32 + tj * 16 + fr] = acc[ti][tj][rr];
        __syncthreads();
        float v[8];
        *(float4*)&v[0] = *(const float4*)&rep[mr * 32 + nc];
        *(float4*)&v[4] = *(const float4*)&rep[mr * 32 + nc + 4];
        const int gm = r * C_ + i0 + wm + ti * 16 + mr;
        const int gn = h * DK_ + wn + nc;
        u16x8 H8, L8;
        #pragma unroll
        for (int jj = 0; jj < 8; ++jj) { HL e = split2(v[jj]); H8[jj] = e.h; L8[jj] = e.l; }
        *(u16x8*)&Ch[(size_t)gm * E_ + gn] = H8;
        *(u16x8*)&Cl[(size_t)gm * E_ + gn] = L8;
    }
}

// ---------------------------------------------------------------------------
// Output projection: A = context (pre-split), B = Wo fp32, out fp32 + bias.
// Block 128 x 256, same core.
// ---------------------------------------------------------------------------
__global__ __launch_bounds__(256, 2) void oproj_gemm(
    const ush* __restrict__ Ah, const ush* __restrict__ Al,
    const float* __restrict__ W, const float* __restrict__ bias,
    float* __restrict__ Y)
{
    __shared__ __align__(16) ush smem[30720];
    ush* AsH = smem;
    ush* AsL = smem + 5120;
    ush* BsH = smem + 10240;
    ush* BsL = smem + 20480;

    const int n0 = blockIdx.x * 256;
    const int m0 = blockIdx.y * 128;

    const int tid = threadIdx.x;
    const int wave = tid >> 6, lane = tid & 63;
    const int wm = (wave & 1) * 64, wn = (wave >> 1) * 128;
    const int fr = lane & 15, kq = (lane >> 4) * 8;
    const int arow = tid >> 1, koff = (tid & 1) * 16;

    f32x4 acc[4][8] = {};

    for (int k0 = 0; k0 < E_; k0 += 32) {
        const size_t ab = (size_t)(m0 + arow) * E_ + k0 + koff;
        stage16_pre(AsH, AsL, arow * LP + koff, Ah + ab, Al + ab);
        #pragma unroll
        for (int rr = 0; rr < 2; ++rr) {
            const int brow = rr * 128 + arow;
            stage16_f32(BsH, BsL, brow * LP + koff, W + (size_t)(n0 + brow) * E_ + k0 + koff);
        }
        __syncthreads();
        mma_step(AsH, AsL, BsH, BsL, wm, wn, fr, kq, acc);
        __syncthreads();
    }

    __syncthreads();
    float* rep = (float*)smem + wave * (16 * REPP);
    const int mr = lane >> 2, q = lane & 3;
    #pragma unroll
    for (int ti = 0; ti < 4; ++ti) {
        float v[32];
        repack_ti(rep, acc[ti], lane, v);
        const int gm = m0 + wm + ti * 16 + mr;
        const int gc = n0 + wn + q * 32;
        #pragma unroll
        for (int c = 0; c < 8; ++c) {
            float4 b4 = *(const float4*)&bias[gc + 4 * c];
            float4 o;
            o.x = v[4*c+0] + b4.x; o.y = v[4*c+1] + b4.y;
            o.z = v[4*c+2] + b4.z; o.w = v[4*c+3] + b4.w;
            *(float4*)&Y[(size_t)gm * E_ + gc + 4 * c] = o;
        }
    }
}

// ---------------------------------------------------------------------------
extern "C" void kernel_launch(void* const* d_in, const int* in_sizes, int n_in,
                              void* d_out, int out_size, void* d_ws, size_t ws_size,
                              hipStream_t stream)
{
    (void)in_sizes; (void)n_in; (void)out_size; (void)ws_size;

    const float* x  = (const float*)d_in[0];
    const float* Wq = (const float*)d_in[1];
    const float* bq = (const float*)d_in[2];
    const float* Wk = (const float*)d_in[3];
    const float* bk = (const float*)d_in[4];
    const float* Wv = (const float*)d_in[5];
    const float* bv = (const float*)d_in[6];
    const float* Wo = (const float*)d_in[7];
    const float* bo = (const float*)d_in[8];

    float* out   = (float*)d_out;
    float* probs = out + (size_t)T_ * E_;
    float* part  = out;                     // 32*H*C*C floats == T*E floats exactly

    // ws: 6 planar bf16 buffers of T_*E_ ushorts = 302 MB (unchanged from R3)
    const size_t QN = (size_t)T_ * E_;
    ush* qh = (ush*)d_ws;
    ush* ql = qh + QN;
    ush* kh = ql + QN;
    ush* kl = kh + QN;
    ush* vh = kl + QN;
    ush* vl = vh + QN;
    ush* ph = kh;                 // reuse k region (dead after attn)
    ush* pl = kh + (size_t)H_ * C_ * C_;
    ush* ch = qh;                 // reuse q region (dead after attn)
    ush* cl = ql;

    const float scaling = 0.125f / sqrtf(128.0f);   // DK^-0.5 / sqrt(R)

    dim3 blk(256);
    // Fused QKV projection (n-major grid.x so consecutive blocks share A panel)
    qkv_gemm<<<dim3(2304 / 256, T_ / 128), blk, 0, stream>>>(
        x, Wq, bq, Wk, bk, Wv, bv, scaling, qh, ql, kh, kl, vh, vl);

    // Pooled attention logits -> 32 deterministic partials in out region
    attn2<<<dim3(C_ / 128, H_ * RS_), blk, 0, stream>>>(qh, ql, kh, kl, part);

    // Reduce partials + shared softmax
    softmax_split<<<dim3(H_ * C_), blk, 0, stream>>>(part, probs, ph, pl);

    // Context and output projection
    ctx_mfma<<<dim3(C_ / 128, R_, H_), blk, 0, stream>>>(ph, pl, vh, vl, ch, cl);
    oproj_gemm<<<dim3(E_ / 256, T_ / 128), blk, 0, stream>>>(ch, cl, Wo, bo, out);
}